// Round 7
// baseline (1777.792 us; speedup 1.0000x reference)
//
#include <hip/hip_runtime.h>

#define NN 10000
#define BB 8
#define MROWS 80000   // BB*NN

typedef float f32x4 __attribute__((ext_vector_type(4)));
typedef unsigned int u32x4 __attribute__((ext_vector_type(4)));
typedef _Float16 f16;
typedef _Float16 f16x8 __attribute__((ext_vector_type(8)));

typedef __attribute__((address_space(1))) void as1_void;
typedef __attribute__((address_space(3))) void as3_void;

static __device__ __forceinline__ void gl_lds16(const void* g, void* l){
  __builtin_amdgcn_global_load_lds((as1_void*)g, (as3_void*)l, 16, 0, 0);
}

// ---------------- CSR build ----------------
__global__ void k_count(const int* __restrict__ dst, int E, int* __restrict__ counts){
  int i = blockIdx.x * blockDim.x + threadIdx.x;
  if(i < E) atomicAdd(&counts[dst[i]], 1);
}

__global__ void k_scan(const int* __restrict__ counts, int* __restrict__ rp){
  __shared__ int buf[1024];
  __shared__ int carry;
  const int t = threadIdx.x;
  if(t == 0){ carry = 0; rp[0] = 0; }
  __syncthreads();
  for(int base = 0; base < NN; base += 1024){
    int v = (base + t < NN) ? counts[base + t] : 0;
    buf[t] = v;
    __syncthreads();
    for(int off = 1; off < 1024; off <<= 1){
      int x = (t >= off) ? buf[t - off] : 0;
      __syncthreads();
      buf[t] += x;
      __syncthreads();
    }
    if(base + t < NN) rp[base + t + 1] = carry + buf[t];
    __syncthreads();
    if(t == 0) carry += buf[1023];
    __syncthreads();
  }
}

__global__ void k_fill(const int* __restrict__ dst, int E, const int* __restrict__ rp,
                       int* __restrict__ cursor, int* __restrict__ ci){
  int i = blockIdx.x * blockDim.x + threadIdx.x;
  if(i < E){
    int d = dst[i];
    int p = rp[d] + atomicAdd(&cursor[d], 1);
    ci[p] = i;   // edge id, sorted deterministically afterwards
  }
}

__global__ void k_sort_rows(const int* __restrict__ rp, int* __restrict__ ci, float* __restrict__ vw,
                            const int* __restrict__ esrc, const float* __restrict__ ew){
  const int n = blockIdx.x * blockDim.x + threadIdx.x;
  if(n >= NN) return;
  const int s = rp[n], e = rp[n + 1];
  for(int i = s; i < e - 1; ++i){           // selection sort by edge id (unique) -> deterministic
    int mj = i, mv = ci[i];
    for(int j = i + 1; j < e; ++j){
      int v = ci[j];
      if(v < mv){ mv = v; mj = j; }
    }
    ci[mj] = ci[i]; ci[i] = mv;
  }
  for(int p = s; p < e; ++p){
    int eid = ci[p];
    ci[p] = esrc[eid];
    vw[p] = ew[eid];
  }
}

// ---------------- f32 -> fp16 convert (8 at a time) ----------------
__global__ void k_cvt(const float4* __restrict__ in, f16x8* __restrict__ out, int n8){
  int i = blockIdx.x * blockDim.x + threadIdx.x;
  if(i >= n8) return;
  float4 v0 = in[2 * i], v1 = in[2 * i + 1];
  f16x8 o;
  o[0] = (f16)v0.x; o[1] = (f16)v0.y; o[2] = (f16)v0.z; o[3] = (f16)v0.w;
  o[4] = (f16)v1.x; o[5] = (f16)v1.y; o[6] = (f16)v1.z; o[7] = (f16)v1.w;
  out[i] = o;
}

// Pack weights transposed to fp16: Wt[c][k] = W[k][c].
__global__ void k_pack_w(const float* __restrict__ Wi, const float* __restrict__ LWi,
                         const float* __restrict__ Wb, const float* __restrict__ LWb,
                         f16* __restrict__ dh){
  const int T0 = 512 * 512;
  const int TOT = T0 + 12 * 512 * 256;
  int i = blockIdx.x * blockDim.x + threadIdx.x;
  if(i >= TOT) return;
  float v;
  if(i < T0){
    int c = i >> 9, k = i & 511;
    v = (c < 256) ? Wi[k * 256 + c] : LWi[k * 256 + (c - 256)];
  } else {
    int j = i - T0;
    int li = j >> 17;          // 512*256 = 2^17
    int r = j & 131071;
    int c = r >> 8, k = r & 255;
    const float* src = (c < 256) ? (Wb + (size_t)li * 65536) : (LWb + (size_t)li * 65536);
    v = src[k * 256 + (c & 255)];
  }
  dh[i] = (f16)v;
}

// ---------------- dual GEMM (fp16): by=0 -> Sup, by=1 -> Loc ----
__global__ __launch_bounds__(256) void k_gemm_dual(
    const f16* __restrict__ A, const f16* __restrict__ Bt,
    f16* __restrict__ Sup, f16* __restrict__ Loc, int K, int nblk)
{
  __shared__ f16 As[2][2048];   // 2 x 4 KB  (64 rows x 32 k)
  __shared__ f16 Bs[2][8192];   // 2 x 16 KB (256 rows x 32 k)
  const int t = threadIdx.x;
  const int pid = blockIdx.x;
  const int q = nblk >> 3, r = nblk & 7;
  const int xcd = pid & 7, sl = pid >> 3;
  const int wg = (xcd < r ? xcd * (q + 1) : r * (q + 1) + (xcd - r) * q) + sl;
  const int m0 = (wg >> 1) << 6;
  const int by = wg & 1;
  const int n0 = by << 8;
  const int lane = t & 63, wv = t >> 6;
  const int rA = lane & 15, g = lane >> 4;
  f32x4 acc[4][4] = {};
  const int nsteps = K >> 5;
  const int rowt = t >> 2;                         // 0..63
  const int csw  = (t & 3) ^ ((rowt >> 1) & 3);    // pre-swizzled source chunk
  const int cbt  = csw << 3;                       // f16 offset 0/8/16/24

  auto STAGE = [&](int s, int buf){
    const int k0 = s << 5;
    const size_t aoff = (size_t)(m0 + rowt) * K + k0 + cbt;
    gl_lds16(A + aoff, (char*)As[buf] + t * 16);
    #pragma unroll
    for(int qq = 0; qq < 4; ++qq){
      const size_t boff = (size_t)(n0 + qq * 64 + rowt) * K + k0 + cbt;
      gl_lds16(Bt + boff, (char*)Bs[buf] + qq * 4096 + t * 16);
    }
  };

  STAGE(0, 0);
  int cur = 0;
  const int slotx = (rA >> 1) & 3;        // read-side XOR base

  for(int s = 0; s < nsteps; ++s){
    __builtin_amdgcn_sched_barrier(0);
    if(s + 1 < nsteps){
      STAGE(s + 1, cur ^ 1);
      asm volatile("s_waitcnt vmcnt(5)" ::: "memory");
    } else {
      asm volatile("s_waitcnt vmcnt(0)" ::: "memory");
    }
    __builtin_amdgcn_s_barrier();
    __builtin_amdgcn_sched_barrier(0);

    f16x8 av[4], bv[4];
    #pragma unroll
    for(int mi = 0; mi < 4; ++mi){
      const int ao = (mi * 16 + rA) * 32 + ((g ^ slotx) << 3);
      av[mi] = *(const f16x8*)(As[cur] + ao);
    }
    #pragma unroll
    for(int ni = 0; ni < 4; ++ni){
      const int bo = wv * 2048 + (ni * 16 + rA) * 32 + ((g ^ slotx) << 3);
      bv[ni] = *(const f16x8*)(Bs[cur] + bo);
    }
    #pragma unroll
    for(int mi = 0; mi < 4; ++mi){
      #pragma unroll
      for(int ni = 0; ni < 4; ++ni){
        acc[mi][ni] = __builtin_amdgcn_mfma_f32_16x16x32_f16(av[mi], bv[ni], acc[mi][ni], 0, 0, 0);
      }
    }
    __builtin_amdgcn_sched_barrier(0);
    __builtin_amdgcn_s_barrier();
    cur ^= 1;
  }

  f16* dst = (by == 0) ? Sup : Loc;
  const int wn = wv << 6;
  #pragma unroll
  for(int mi = 0; mi < 4; ++mi){
    const int rowb = m0 + mi * 16 + g * 4;
    #pragma unroll
    for(int ni = 0; ni < 4; ++ni){
      const int col = wn + ni * 16 + rA;
      #pragma unroll
      for(int r2 = 0; r2 < 4; ++r2){
        dst[(size_t)(rowb + r2) * 256 + col] = (f16)acc[mi][ni][r2];
      }
    }
  }
}

// ---------------- aggregation, XCD-batch-pinned, D-split, nt streams ----------------
// grid = 10000 blocks: pid<5000 -> d-half 0, else half 1; batch = pid%8.
// Sup gather panel (2.56MB per batch-half) is kept L2-resident; all streaming
// accesses (Loc, Hprev, Hn, hout) are NON-TEMPORAL so they don't evict it.
// mode 0: Hnext = fp16(t)
// mode 2: Hnext = fp16((Hprev + t)*0.5)   (in-place allowed)
// mode 3: hout(f32) = (Hprev + t)*0.5     (last layer)
__global__ __launch_bounds__(256) void k_agg(
    const f16* __restrict__ Sup, const f16* __restrict__ Loc,
    const float* __restrict__ bias,
    const int* __restrict__ rp, const int* __restrict__ ci, const float* __restrict__ vw,
    const f16* __restrict__ Hprev, f16* __restrict__ Hnext,
    float* __restrict__ hout, const int mode)
{
  const int pid = blockIdx.x;
  const int half = (pid >= 5000) ? 1 : 0;
  const int rem = pid - half * 5000;
  const int b = rem & 7;
  const int grp = rem >> 3;               // 0..624
  const int t = threadIdx.x;
  const int j = t >> 4;                   // node within group (0..15)
  const int tt = t & 15;
  const int n = grp * 16 + j;
  const int d0 = half * 128 + tt * 8;
  const size_t rowbase = ((size_t)b * NN + n) * 256 + d0;
  float a[8];
  {
    const u32x4 lraw = __builtin_nontemporal_load((const u32x4*)(Loc + rowbase));
    const f16x8 lv = *(const f16x8*)&lraw;
    float4 q0 = *(const float4*)(bias + d0);
    float4 q1 = *(const float4*)(bias + d0 + 4);
    a[0] = (float)lv[0] + q0.x; a[1] = (float)lv[1] + q0.y;
    a[2] = (float)lv[2] + q0.z; a[3] = (float)lv[3] + q0.w;
    a[4] = (float)lv[4] + q1.x; a[5] = (float)lv[5] + q1.y;
    a[6] = (float)lv[6] + q1.z; a[7] = (float)lv[7] + q1.w;
  }
  const int s = rp[n], e = rp[n + 1];
  const size_t bb = (size_t)b * NN * 256 + d0;
  for(int i = s; i < e; ++i){
    const int src = ci[i];
    const float w = vw[i];
    const f16x8 sv = *(const f16x8*)(Sup + bb + (size_t)src * 256);
    a[0] = fmaf(w, (float)sv[0], a[0]);
    a[1] = fmaf(w, (float)sv[1], a[1]);
    a[2] = fmaf(w, (float)sv[2], a[2]);
    a[3] = fmaf(w, (float)sv[3], a[3]);
    a[4] = fmaf(w, (float)sv[4], a[4]);
    a[5] = fmaf(w, (float)sv[5], a[5]);
    a[6] = fmaf(w, (float)sv[6], a[6]);
    a[7] = fmaf(w, (float)sv[7], a[7]);
  }
  if(mode >= 2){
    const u32x4 hraw = __builtin_nontemporal_load((const u32x4*)(Hprev + rowbase));
    const f16x8 hp = *(const f16x8*)&hraw;
    #pragma unroll
    for(int k = 0; k < 8; ++k) a[k] = (a[k] + (float)hp[k]) * 0.5f;
  }
  if(mode == 3){
    f32x4 o0 = {a[0], a[1], a[2], a[3]};
    f32x4 o1 = {a[4], a[5], a[6], a[7]};
    __builtin_nontemporal_store(o0, (f32x4*)(hout + rowbase));
    __builtin_nontemporal_store(o1, (f32x4*)(hout + rowbase + 4));
    return;
  }
  f16x8 o;
  #pragma unroll
  for(int k = 0; k < 8; ++k) o[k] = (f16)a[k];
  __builtin_nontemporal_store(*(const u32x4*)&o, (u32x4*)(Hnext + rowbase));
}

// ---------------- output layer (Dout=3), f32 throughout ----------------
__global__ __launch_bounds__(256) void k_out_sup(const float* __restrict__ h,
    const float* __restrict__ Wo, float* __restrict__ sup3){
  const int gid = blockIdx.x * 4 + (threadIdx.x >> 6);
  const int lane = threadIdx.x & 63;
  if(gid >= MROWS) return;
  const float4 v = *(const float4*)(h + (size_t)gid * 256 + lane * 4);
  const float hv[4] = {v.x, v.y, v.z, v.w};
  float p0 = 0.f, p1 = 0.f, p2 = 0.f;
  #pragma unroll
  for(int j = 0; j < 4; ++j){
    const int k = lane * 4 + j;
    p0 = fmaf(hv[j], Wo[k * 3 + 0], p0);
    p1 = fmaf(hv[j], Wo[k * 3 + 1], p1);
    p2 = fmaf(hv[j], Wo[k * 3 + 2], p2);
  }
  #pragma unroll
  for(int off = 32; off; off >>= 1){
    p0 += __shfl_xor(p0, off, 64);
    p1 += __shfl_xor(p1, off, 64);
    p2 += __shfl_xor(p2, off, 64);
  }
  if(lane == 0){
    float* o = sup3 + (size_t)gid * 3;
    o[0] = p0; o[1] = p1; o[2] = p2;
  }
}

__global__ __launch_bounds__(256) void k_out_final(const float* __restrict__ h,
    const float* __restrict__ LWo, const float* __restrict__ bo,
    const int* __restrict__ rp, const int* __restrict__ ci, const float* __restrict__ vw,
    const float* __restrict__ sup3, float* __restrict__ out){
  const int gid = blockIdx.x * 4 + (threadIdx.x >> 6);
  const int lane = threadIdx.x & 63;
  if(gid >= MROWS) return;
  const int b = gid / NN, n = gid % NN;
  const float4 v = *(const float4*)(h + (size_t)gid * 256 + lane * 4);
  const float hv[4] = {v.x, v.y, v.z, v.w};
  float p0 = 0.f, p1 = 0.f, p2 = 0.f;
  #pragma unroll
  for(int j = 0; j < 4; ++j){
    const int k = lane * 4 + j;
    p0 = fmaf(hv[j], LWo[k * 3 + 0], p0);
    p1 = fmaf(hv[j], LWo[k * 3 + 1], p1);
    p2 = fmaf(hv[j], LWo[k * 3 + 2], p2);
  }
  const int s = rp[n], e = rp[n + 1];
  for(int i = s + lane; i < e; i += 64){
    const int src = ci[i];
    const float w = vw[i];
    const float* sp = sup3 + ((size_t)b * NN + src) * 3;
    p0 = fmaf(w, sp[0], p0);
    p1 = fmaf(w, sp[1], p1);
    p2 = fmaf(w, sp[2], p2);
  }
  #pragma unroll
  for(int off = 32; off; off >>= 1){
    p0 += __shfl_xor(p0, off, 64);
    p1 += __shfl_xor(p1, off, 64);
    p2 += __shfl_xor(p2, off, 64);
  }
  if(lane == 0){
    float* o = out + (size_t)gid * 3;
    o[0] = p0 + bo[0]; o[1] = p1 + bo[1]; o[2] = p2 + bo[2];
  }
}

// ---------------- host ----------------
extern "C" void kernel_launch(void* const* d_in, const int* in_sizes, int n_in,
                              void* d_out, int out_size, void* d_ws, size_t ws_size,
                              hipStream_t stream) {
  const float* x     = (const float*)d_in[0];
  const int*   esrc  = (const int*)d_in[1];
  const int*   edst  = (const int*)d_in[2];
  const float* ew    = (const float*)d_in[3];
  const float* W_in  = (const float*)d_in[4];
  const float* LW_in = (const float*)d_in[5];
  const float* b_in  = (const float*)d_in[6];
  const float* W_blk = (const float*)d_in[7];
  const float* LW_blk= (const float*)d_in[8];
  const float* b_blk = (const float*)d_in[9];
  const float* W_out = (const float*)d_in[10];
  const float* LW_out= (const float*)d_in[11];
  const float* b_out = (const float*)d_in[12];
  const int E = in_sizes[1];

  float* outF  = (float*)d_out;
  float* xout  = outF;                  // [B,N,3]
  float* hOut  = outF + 240000;         // h region [B,N,256] f32, written at last layer
  f16* x16 = (f16*)hOut;                // doubles as fp16-x scratch before layer 0

  char* ws = (char*)d_ws;
  size_t off = 0;
  auto alloc = [&](size_t bytes) -> char* {
    char* p = ws + off;
    off += (bytes + 255) & ~(size_t)255;
    return p;
  };
  const size_t HB = (size_t)20480000 * 2;           // one fp16 activation buffer
  f16* Ha  = (f16*)alloc(HB);
  f16* Hb  = (f16*)alloc(HB);
  f16* Sup = (f16*)alloc(HB);
  f16* Loc = (f16*)alloc(HB);
  const int WTOT = 512 * 512 + 12 * 512 * 256;
  f16* Wt = (f16*)alloc((size_t)WTOT * 2);
  float* sup3    = (float*)alloc((size_t)240000 * 4);
  int*   counts  = (int*)alloc((size_t)2 * NN * 4);   // counts + cursor contiguous
  int*   cursor  = counts + NN;
  int*   rp      = (int*)alloc((size_t)(NN + 1) * 4);
  int*   ci      = (int*)alloc((size_t)E * 4);
  float* vw      = (float*)alloc((size_t)E * 4);
  (void)ws_size; (void)n_in; (void)out_size;

  // CSR build (deterministic: rows sorted by edge id)
  hipMemsetAsync(counts, 0, (size_t)2 * NN * 4, stream);
  k_count<<<(E + 255) / 256, 256, 0, stream>>>(edst, E, counts);
  k_scan<<<1, 1024, 0, stream>>>(counts, rp);
  k_fill<<<(E + 255) / 256, 256, 0, stream>>>(edst, E, rp, cursor, ci);
  k_sort_rows<<<(NN + 255) / 256, 256, 0, stream>>>(rp, ci, vw, esrc, ew);

  // convert x -> fp16 ; pack transposed weights fp16
  k_cvt<<<(5120000 + 255) / 256, 256, 0, stream>>>((const float4*)x, (f16x8*)x16, 5120000);
  k_pack_w<<<(WTOT + 255) / 256, 256, 0, stream>>>(W_in, LW_in, W_blk, LW_blk, Wt);

  const int NBLK = 2500;    // GEMM: 1250 m-blocks x 2 (Sup/Loc)
  const int ABLK = 10000;   // agg: 2 halves x 8 batches x 625 groups
  // layer 0 (K=512): h0 = t
  k_gemm_dual<<<NBLK, 256, 0, stream>>>(x16, Wt, Sup, Loc, 512, NBLK);
  k_agg<<<ABLK, 256, 0, stream>>>(Sup, Loc, b_in, rp, ci, vw, Ha, Ha, xout, 0);

  const f16* Wm = Wt + 512 * 512;
  for(int l = 0; l < 6; ++l){
    const int li0 = 2 * l, li1 = 2 * l + 1;
    k_gemm_dual<<<NBLK, 256, 0, stream>>>(Ha, Wm + (size_t)li0 * 131072, Sup, Loc, 256, NBLK);
    k_agg<<<ABLK, 256, 0, stream>>>(Sup, Loc, b_blk + li0 * 256, rp, ci, vw, Ha, Hb, xout, 0);
    k_gemm_dual<<<NBLK, 256, 0, stream>>>(Hb, Wm + (size_t)li1 * 131072, Sup, Loc, 256, NBLK);
    k_agg<<<ABLK, 256, 0, stream>>>(Sup, Loc, b_blk + li1 * 256, rp, ci, vw, Ha, Ha, hOut, (l == 5) ? 3 : 2);
  }

  // output layer, f32 from hOut (d_out h region)
  k_out_sup<<<MROWS / 4, 256, 0, stream>>>(hOut, W_out, sup3);
  k_out_final<<<MROWS / 4, 256, 0, stream>>>(hOut, LW_out, b_out, rp, ci, vw, sup3, xout);
}